// Round 8
// baseline (9081.690 us; speedup 1.0000x reference)
//
#include <hip/hip_runtime.h>
#include <hip/hip_bf16.h>

#define B_ 64
#define T_ 512
#define O_ 512
#define N_ 2048
#define NWG 256
#define NTHR 256
#define EPSF 1e-5f

typedef __attribute__((ext_vector_type(8))) short short8v;
typedef __attribute__((ext_vector_type(4))) float f32x4;
typedef unsigned short u16;
typedef unsigned long long u64;

__device__ __forceinline__ u16 f2bf(float f) {
    union { float f; unsigned u; } v; v.f = f;
    unsigned r = v.u + 0x7fffu + ((v.u >> 16) & 1u);   // RNE
    return (u16)(r >> 16);
}

// sc1 (agent-scope, LLC-coherent) helpers — relaxed, no fences, no RMW
__device__ __forceinline__ u64 ldg_sc1_u64(const void* p) {
    return __hip_atomic_load((const u64*)p, __ATOMIC_RELAXED, __HIP_MEMORY_SCOPE_AGENT);
}
__device__ __forceinline__ float ldg_sc1_f32(const float* p) {
    return __hip_atomic_load(p, __ATOMIC_RELAXED, __HIP_MEMORY_SCOPE_AGENT);
}
__device__ __forceinline__ unsigned ldg_sc1_u32(const unsigned* p) {
    return __hip_atomic_load(p, __ATOMIC_RELAXED, __HIP_MEMORY_SCOPE_AGENT);
}
__device__ __forceinline__ void stg_sc1_f32(float* p, float v) {
    __hip_atomic_store(p, v, __ATOMIC_RELAXED, __HIP_MEMORY_SCOPE_AGENT);
}
__device__ __forceinline__ void stg_sc1_u32(unsigned* p, unsigned v) {
    __hip_atomic_store(p, v, __ATOMIC_RELAXED, __HIP_MEMORY_SCOPE_AGENT);
}
__device__ __forceinline__ void stg_sc1_u64(u64* p, u64 v) {
    __hip_atomic_store(p, v, __ATOMIC_RELAXED, __HIP_MEMORY_SCOPE_AGENT);
}

// ---------- init: W fp32 [1024][2048] -> wt bf16 [2048 col][1024 k] ----------
__global__ void k_init_wt(const float* __restrict__ W, u16* __restrict__ wt) {
    __shared__ u16 tile[64][65];
    const int tk = (blockIdx.x >> 5) * 64;
    const int tn = (blockIdx.x & 31) * 64;
    const int r = threadIdx.x >> 6, c = threadIdx.x & 63;
#pragma unroll
    for (int i = 0; i < 16; ++i)
        tile[r + 4 * i][c] = f2bf(W[(size_t)(tk + r + 4 * i) * N_ + tn + c]);
    __syncthreads();
#pragma unroll
    for (int i = 0; i < 16; ++i)
        wt[(size_t)(tn + r + 4 * i) * 1024 + tk + c] = tile[c][r + 4 * i];
}

__global__ void k_zero_flags(unsigned* flags) {
    stg_sc1_u32(flags + threadIdx.x, 0u);
}

// ---------- persistent LN-LSTM: 256 wgs x 256 thr, wave-specialized ----------
// wg: cg = wgid>>1 (16 cols), rh = wgid&1 (32 rows).  waves 0,1: x-half K0-511;
// waves 2,3: h-half K512-1023 + phase 2 (row b=wgid>>2, o-quarter wgid&3).
__global__ __launch_bounds__(NTHR, 1)
void k_persist(const float* __restrict__ x, const u16* __restrict__ wt,
               const float* __restrict__ bias, const float* __restrict__ lnw,
               const float* __restrict__ lnb, const float* __restrict__ hx,
               const float* __restrict__ cx, u16* hbuf, float* comb,
               float* statsp, unsigned* flags, float* __restrict__ out) {
    __shared__ float ldsT[2][16][17];   // h-half partial tiles (wave2->0, wave3->1)
    __shared__ float sred[4];

    const int tid = threadIdx.x, wgid = blockIdx.x;
    const int cg = wgid >> 1, rh = wgid & 1;
    const int w = tid >> 6, l = tid & 63;
    const int rl = l & 15, kg = l >> 4;
    const bool hw = (w >= 2);                 // h-half + phase-2 wave
    const int tile = w & 1;                   // row-tile within the 32-row half
    const int ar = rh * 32 + tile * 16;       // first A/C row of this wave
    const int myrow = ar + rl;                // A row this lane loads
    const int khalf = w >> 1;                 // 0: k 0-511, 1: k 512-1023

    // ---- W fragments into registers (16 cols x 512 k per wave) ----
    short8v bw[16];
#pragma unroll
    for (int kc = 0; kc < 16; ++kc)
        bw[kc] = *(const short8v*)(wt + (size_t)(cg * 16 + rl) * 1024 +
                                   khalf * 512 + kc * 32 + kg * 8);
    const float bcol = bias[cg * 16 + rl];

    // ---- phase-2 identity (waves 2,3): row b, o-quarter ----
    const int b = wgid >> 2;
    const int pi = tid - 128;                 // 0..127 for hw waves
    const int o = (wgid & 3) * 128 + pi;
    float lw0, lw1, lw2, lw3, lb0, lb1, lb2, lb3, creg = 0.f;
    if (hw) {
        lw0 = lnw[o]; lw1 = lnw[512 + o]; lw2 = lnw[1024 + o]; lw3 = lnw[1536 + o];
        lb0 = lnb[o]; lb1 = lnb[512 + o]; lb2 = lnb[1024 + o]; lb3 = lnb[1536 + o];
        creg = cx[o];
        float h0v = hx[o];
        float hn = __shfl_xor(h0v, 1);
        if (!(pi & 1)) {
            unsigned hp = (unsigned)f2bf(h0v) | ((unsigned)f2bf(hn) << 16);
            stg_sc1_u32((unsigned*)(hbuf + b * O_ + o), hp);
        }
    }

    // ---- flat one-hop barrier: 256 flags, wave-0 polls 4 flags/lane ----
    auto arrive = [&](unsigned g) {
        asm volatile("s_waitcnt vmcnt(0)" ::: "memory");
        __syncthreads();
        if (tid == 0) stg_sc1_u32(flags + wgid, g);
    };
    auto wait = [&](unsigned g) {
        if (tid < 64) {
            const unsigned* f = flags + tid * 4;
            for (;;) {
                unsigned a0 = ldg_sc1_u32(f);
                unsigned a1 = ldg_sc1_u32(f + 1);
                unsigned a2 = ldg_sc1_u32(f + 2);
                unsigned a3 = ldg_sc1_u32(f + 3);
                if (a0 >= g && a1 >= g && a2 >= g && a3 >= g) break;
            }
        }
        __syncthreads();
    };

    // x-half GEMM (waves 0,1): 16 K-chunks, fp32 load + convert
    auto xgemm = [&](int t, f32x4& c0, f32x4& c1) {
        const float* xrow = x + (size_t)myrow * (T_ * 512) + (size_t)t * 512;
#pragma unroll
        for (int kc = 0; kc < 16; ++kc) {
            int kloc = kc * 32 + kg * 8;
            float4 u0 = *(const float4*)(xrow + kloc);
            float4 u1 = *(const float4*)(xrow + kloc + 4);
            short8v a;
            a[0] = (short)f2bf(u0.x); a[1] = (short)f2bf(u0.y);
            a[2] = (short)f2bf(u0.z); a[3] = (short)f2bf(u0.w);
            a[4] = (short)f2bf(u1.x); a[5] = (short)f2bf(u1.y);
            a[6] = (short)f2bf(u1.z); a[7] = (short)f2bf(u1.w);
            if (kc & 1) c1 = __builtin_amdgcn_mfma_f32_16x16x32_bf16(a, bw[kc], c1, 0, 0, 0);
            else        c0 = __builtin_amdgcn_mfma_f32_16x16x32_bf16(a, bw[kc], c0, 0, 0, 0);
        }
    };
    // h-half GEMM (waves 2,3): cached loads from rotating slot
    auto hgemm = [&](const u16* hslot, f32x4& c0, f32x4& c1) {
        const u16* hrow = hslot + (myrow << 9);
#pragma unroll
        for (int kc = 0; kc < 16; ++kc) {
            short8v a = *(const short8v*)(hrow + kc * 32 + kg * 8);
            if (kc & 1) c1 = __builtin_amdgcn_mfma_f32_16x16x32_bf16(a, bw[kc], c1, 0, 0, 0);
            else        c0 = __builtin_amdgcn_mfma_f32_16x16x32_bf16(a, bw[kc], c0, 0, 0, 0);
        }
    };

    unsigned gen = 1;
    arrive(gen);                              // h0 published
    f32x4 xa0 = {0.f,0.f,0.f,0.f}, xa1 = {0.f,0.f,0.f,0.f};
    if (!hw) xgemm(0, xa0, xa1);
    wait(gen); gen++;

    for (int t = 0; t < T_; ++t) {
        // ---- h-half GEMM + tile handoff ----
        if (hw) {
            f32x4 h0a = {0.f,0.f,0.f,0.f}, h1a = {0.f,0.f,0.f,0.f};
            hgemm(hbuf + (size_t)t * (B_ * O_), h0a, h1a);
            f32x4 hacc = h0a + h1a;
#pragma unroll
            for (int j = 0; j < 4; ++j)
                ldsT[tile][kg * 4 + j][rl] = hacc[j];
        }
        __syncthreads();

        // ---- combine + stats + comb store (waves 0,1) ----
        if (!hw) {
            float vv[4], sj[4], qj[4];
#pragma unroll
            for (int j = 0; j < 4; ++j) {
                float v = xa0[j] + xa1[j] + ldsT[tile][kg * 4 + j][rl] + bcol;
                vv[j] = v; sj[j] = v; qj[j] = v * v;
            }
#pragma unroll
            for (int m = 1; m < 16; m <<= 1) {
#pragma unroll
                for (int j = 0; j < 4; ++j) {
                    sj[j] += __shfl_xor(sj[j], m);
                    qj[j] += __shfl_xor(qj[j], m);
                }
            }
#pragma unroll
            for (int j = 0; j < 4; ++j)
                stg_sc1_f32(comb + (size_t)(ar + kg * 4 + j) * N_ + cg * 16 + rl, vv[j]);
            if (rl == 0) {
#pragma unroll
                for (int j = 0; j < 4; ++j) {
                    union { float f[2]; u64 q; } p;
                    p.f[0] = sj[j]; p.f[1] = qj[j];
                    stg_sc1_u64((u64*)(statsp + ((size_t)(ar + kg * 4 + j) * 128 + cg) * 2), p.q);
                }
            }
        }

        arrive(gen);                          // comb + stats release
        wait(gen); gen++;                     // stats(t) + comb(t) final

        // ---- post-A: phase 2 on waves 2,3 ; x-GEMM(t+1) on waves 0,1 ----
        float cv0, cv1, cv2, cv3, s = 0.f, q = 0.f;
        if (hw) {
            const float* cb = comb + (size_t)b * N_ + o;
            cv0 = ldg_sc1_f32(cb);
            cv1 = ldg_sc1_f32(cb + 512);
            cv2 = ldg_sc1_f32(cb + 1024);
            cv3 = ldg_sc1_f32(cb + 1536);
            union { u64 q64; float f[2]; } p;
            p.q64 = ldg_sc1_u64(statsp + ((size_t)b * 128 + pi) * 2);
            s = p.f[0]; q = p.f[1];
#pragma unroll
            for (int m = 32; m > 0; m >>= 1) {
                s += __shfl_down(s, m);
                q += __shfl_down(q, m);
            }
            if (pi == 0)  { sred[0] = s; sred[1] = q; }
            if (pi == 64) { sred[2] = s; sred[3] = q; }
        }
        __syncthreads();

        if (hw) {
            float S = sred[0] + sred[2], Q = sred[1] + sred[3];
            float mu = S * (1.0f / 2048.0f);
            float var = Q * (1.0f / 2048.0f) - mu * mu;
            float rstd = rsqrtf(var + EPSF);
            float n0v = (cv0 - mu) * rstd * lw0 + lb0;
            float n1v = (cv1 - mu) * rstd * lw1 + lb1;
            float n2v = (cv2 - mu) * rstd * lw2 + lb2;
            float n3v = (cv3 - mu) * rstd * lw3 + lb3;
            float ig = 1.f / (1.f + __expf(-n0v));
            float fg = 1.f / (1.f + __expf(-n1v));
            float og = 1.f / (1.f + __expf(-n2v));
            float e2 = __expf(-2.f * fabsf(n3v));
            float th = copysignf((1.f - e2) / (1.f + e2), n3v);
            creg = fg * creg + ig * th;
            float h = og * creg;
            __builtin_nontemporal_store(h, out + (size_t)b * (T_ * O_) + (size_t)t * O_ + o);
            if (t + 1 < T_) {
                u16* hW = hbuf + (size_t)(t + 1) * (B_ * O_);
                float hn = __shfl_xor(h, 1);
                if (!(pi & 1)) {
                    unsigned hp = (unsigned)f2bf(h) | ((unsigned)f2bf(hn) << 16);
                    stg_sc1_u32((unsigned*)(hW + b * O_ + o), hp);
                }
            }
        } else if (t + 1 < T_) {
            xa0 = f32x4{0.f,0.f,0.f,0.f}; xa1 = f32x4{0.f,0.f,0.f,0.f};
            xgemm(t + 1, xa0, xa1);           // concurrent with phase 2 (other SIMDs)
        }

        if (t == T_ - 1) break;

        arrive(gen);                          // h(t+1) release
        wait(gen); gen++;                     // h(t+1) visible
    }
}

extern "C" void kernel_launch(void* const* d_in, const int* in_sizes, int n_in,
                              void* d_out, int out_size, void* d_ws, size_t ws_size,
                              hipStream_t stream) {
    const float* x    = (const float*)d_in[0];
    const float* W    = (const float*)d_in[1];
    const float* bias = (const float*)d_in[2];
    const float* lnw  = (const float*)d_in[3];
    const float* lnb  = (const float*)d_in[4];
    const float* hx   = (const float*)d_in[5];
    const float* cx   = (const float*)d_in[6];
    float* out = (float*)d_out;

    char* ws = (char*)d_ws;
    u16*      wt     = (u16*)ws;                      // 4 MiB
    u16*      hbuf   = (u16*)(ws + 4194304);          // 32 MiB (512 rotating h slots)
    float*    statsp = (float*)(ws + 37748736);       // 64 KiB [64 rows][128 cg] f2
    float*    comb   = (float*)(ws + 37814272);       // 512 KiB
    unsigned* flags  = (unsigned*)(ws + 38338560);    // 1 KiB (256 flags)

    k_init_wt<<<512, 256, 0, stream>>>(W, wt);
    k_zero_flags<<<1, 256, 0, stream>>>(flags);
    k_persist<<<NWG, NTHR, 0, stream>>>(x, wt, bias, lnw, lnb, hx, cx,
                                        hbuf, comb, statsp, flags, out);
}

// Round 9
// 4623.940 us; speedup vs baseline: 1.9641x; 1.9641x over previous
//
#include <hip/hip_runtime.h>
#include <hip/hip_bf16.h>

#define B_ 64
#define T_ 512
#define O_ 512
#define NWG 256
#define NTHR 256
#define EPSF 1e-5f
#define MAGICW 0x5A17C0DEu

typedef __attribute__((ext_vector_type(8))) short short8v;
typedef __attribute__((ext_vector_type(4))) float f32x4;
typedef __attribute__((ext_vector_type(2))) float f32x2;
typedef unsigned short u16;
typedef unsigned int u32;
typedef unsigned long long u64;

__device__ __forceinline__ u16 f2bf(float f) {
    union { float f; u32 u; } v; v.f = f;
    u32 r = v.u + 0x7fffu + ((v.u >> 16) & 1u);   // RNE
    return (u16)(r >> 16);
}

// ---- sc1 (LLC-coherent, agent scope) helpers: proven r4/r6 ----
__device__ __forceinline__ u32 ldg_sc1_u32(const u32* p) {
    return __hip_atomic_load(p, __ATOMIC_RELAXED, __HIP_MEMORY_SCOPE_AGENT);
}
__device__ __forceinline__ u64 ldg_sc1_u64(const void* p) {
    return __hip_atomic_load((const u64*)p, __ATOMIC_RELAXED, __HIP_MEMORY_SCOPE_AGENT);
}
__device__ __forceinline__ void stg_sc1_u32(u32* p, u32 v) {
    __hip_atomic_store(p, v, __ATOMIC_RELAXED, __HIP_MEMORY_SCOPE_AGENT);
}
__device__ __forceinline__ void stg_sc1_u64(u64* p, u64 v) {
    __hip_atomic_store(p, v, __ATOMIC_RELAXED, __HIP_MEMORY_SCOPE_AGENT);
}

// ---- sc0 (SE scope: bypass L1, read/write own-XCD L2) helpers ----
__device__ __forceinline__ u32 ld_sc0_u32(const u32* p) {
    u32 v;
    asm volatile("global_load_dword %0, %1, off sc0\n\ts_waitcnt vmcnt(0)"
                 : "=v"(v) : "v"(p) : "memory");
    return v;
}
__device__ __forceinline__ f32x2 ld_sc0_f32x2(const float* p) {
    f32x2 v;
    asm volatile("global_load_dwordx2 %0, %1, off sc0\n\ts_waitcnt vmcnt(0)"
                 : "=v"(v) : "v"(p) : "memory");
    return v;
}
__device__ __forceinline__ void st_sc0_u32(u32* p, u32 v) {
    asm volatile("global_store_dword %0, %1, off sc0" :: "v"(p), "v"(v) : "memory");
}
__device__ __forceinline__ void st_sc0_u64(u64* p, u64 v) {
    asm volatile("global_store_dwordx2 %0, %1, off sc0" :: "v"(p), "v"(v) : "memory");
}

// ---------- init: W fp32 [1024][2048] -> wt bf16 [2048 col][1024 k] ----------
__global__ void k_init_wt(const float* __restrict__ W, u16* __restrict__ wt) {
    __shared__ u16 tile[64][65];
    const int tk = (blockIdx.x >> 5) * 64;
    const int tn = (blockIdx.x & 31) * 64;
    const int r = threadIdx.x >> 6, c = threadIdx.x & 63;
#pragma unroll
    for (int i = 0; i < 16; ++i)
        tile[r + 4 * i][c] = f2bf(W[(size_t)(tk + r + 4 * i) * 2048 + tn + c]);
    __syncthreads();
#pragma unroll
    for (int i = 0; i < 16; ++i)
        wt[(size_t)(tn + r + 4 * i) * 1024 + tk + c] = tile[c][r + 4 * i];
}

// ---------- init: x fp32 [b][t][k] -> xbf bf16 [t][b][k] ----------
__global__ void k_init_x(const float* __restrict__ x, u16* __restrict__ xbf) {
    size_t e = ((size_t)blockIdx.x * 256 + threadIdx.x) * 8;
    int b = (int)(e >> 18);
    int r = (int)(e & 262143);
    int t = r >> 9, k = r & 511;
    float4 u0 = *(const float4*)(x + e);
    float4 u1 = *(const float4*)(x + e + 4);
    short8v v;
    v[0] = (short)f2bf(u0.x); v[1] = (short)f2bf(u0.y);
    v[2] = (short)f2bf(u0.z); v[3] = (short)f2bf(u0.w);
    v[4] = (short)f2bf(u1.x); v[5] = (short)f2bf(u1.y);
    v[6] = (short)f2bf(u1.z); v[7] = (short)f2bf(u1.w);
    *(short8v*)(xbf + ((size_t)t * B_ + b) * 512 + k) = v;
}

__global__ void k_zero(u32* ctrl) {   // gflags(256) xcct(256) testw(256) grpfl(512)
    int gid = blockIdx.x * 256 + threadIdx.x;
    if (gid < 2048) stg_sc1_u32(ctrl + gid, 0u);
}

// ---------- persistent LN-LSTM: 8 independent XCD-local groups ----------
__global__ __launch_bounds__(NTHR, 1)
void k_persist(const u16* __restrict__ xbf, const u16* __restrict__ wt,
               const float* __restrict__ bias, const float* __restrict__ lnw,
               const float* __restrict__ lnb, const float* __restrict__ hx,
               const float* __restrict__ cx, u16* hbuf, float* stats,
               u32* ctrl, float* __restrict__ out) {
    __shared__ float ldsC[4][8][17];
    __shared__ f32x2 sp[4][8];
    __shared__ f32x2 sstat[8];
    __shared__ int s_local;

    const int tid = threadIdx.x, wgid = blockIdx.x;
    const int grp = wgid & 7, slot = wgid >> 3;
    const int w = tid >> 6, l = tid & 63;
    const int rl = l & 15, kg = l >> 4;
    const int mycol = 512 * w + 16 * slot + rl;   // col-remap: wave w = gate w

    u32* gflags = ctrl;
    u32* xcct   = ctrl + 256;
    u32* testw  = ctrl + 512;
    u32* grpfl  = ctrl + 1024;

    u16*   grp_h = hbuf + grp * 4096;             // 8 rows x 512 bf16
    float* grp_s = stats + grp * 512;             // 8 rows x 32 slots x (S,Q)
    u32*   gf    = grpfl + grp * 64;              // 32 slot flags, 256B region

    // ---- global (sc1) barrier for init/detection ----
    auto gbar = [&](u32 g) {
        asm volatile("s_waitcnt vmcnt(0)" ::: "memory");
        __syncthreads();
        if (tid == 0) stg_sc1_u32(gflags + wgid, g);
        if (tid < 64) {
            const u32* f = gflags + tid * 4;
            while (!(ldg_sc1_u32(f) >= g && ldg_sc1_u32(f + 1) >= g &&
                     ldg_sc1_u32(f + 2) >= g && ldg_sc1_u32(f + 3) >= g)) {}
        }
        __syncthreads();
    };

    // ---- detection: XCD uniformity + sc0 visibility self-test ----
    u32 xcc;
    asm volatile("s_getreg_b32 %0, hwreg(HW_REG_XCC_ID)" : "=s"(xcc));
    if (tid == 0) stg_sc1_u32(xcct + wgid, xcc + 1u);
    gbar(1);
    bool xcd_ok = true;
    if (tid < 32) {
        u32 v = ldg_sc1_u32(xcct + grp + 8 * tid);
        u32 ref = __shfl(v, 0);
        xcd_ok = __all(v == ref);
    }
    // prime L1 with the (zero) test words
    if (tid < 32) {
        u32 junk;
        asm volatile("global_load_dword %0, %1, off\n\ts_waitcnt vmcnt(0)"
                     : "=v"(junk) : "v"(testw + grp + 8 * tid) : "memory");
        (void)junk;
    }
    gbar(2);
    if (tid == 0) st_sc0_u32(testw + wgid, MAGICW);
    gbar(3);   // includes vmcnt drain of the sc0 store
    if (tid < 32) {
        u32 v = ld_sc0_u32(testw + grp + 8 * tid);
        bool ok = xcd_ok && __all(v == MAGICW);
        if (tid == 0) s_local = ok ? 1 : 0;
    }
    __syncthreads();
    const bool local = (s_local != 0);

    // ---- W fragments into registers (16 cols x full K per wave) ----
    short8v bw[32];
#pragma unroll
    for (int kc = 0; kc < 32; ++kc)
        bw[kc] = *(const short8v*)(wt + (size_t)mycol * 1024 + kc * 32 + kg * 8);
    const float bcol = bias[mycol];

    // ---- phase-2 identity: tid<128 -> (row pb, output po) ----
    const int pb = tid >> 4, pi = tid & 15;
    const int po = 16 * slot + pi;
    float lw0 = 0.f, lw1 = 0.f, lw2 = 0.f, lw3 = 0.f;
    float lb0 = 0.f, lb1 = 0.f, lb2 = 0.f, lb3 = 0.f, creg = 0.f;
    if (tid < 128) {
        lw0 = lnw[po]; lw1 = lnw[512 + po]; lw2 = lnw[1024 + po]; lw3 = lnw[1536 + po];
        lb0 = lnb[po]; lb1 = lnb[512 + po]; lb2 = lnb[1024 + po]; lb3 = lnb[1536 + po];
        creg = cx[po];
        float h0 = hx[po];
        float hn = __shfl_xor(h0, 1);
        if (!(pi & 1)) {
            u32 hp = (u32)f2bf(h0) | ((u32)f2bf(hn) << 16);
            u32* dst = (u32*)(grp_h + pb * 512 + po);
            if (local) st_sc0_u32(dst, hp); else stg_sc1_u32(dst, hp);
        }
    }

    // ---- group barrier (intra-XCD when local) ----
    auto g_arrive = [&](u32 g) {
        asm volatile("s_waitcnt vmcnt(0)" ::: "memory");
        __syncthreads();
        if (tid == 0) { if (local) st_sc0_u32(gf + slot, g); else stg_sc1_u32(gf + slot, g); }
    };
    auto g_wait = [&](u32 g) {
        if (tid < 32) {
            for (;;) {
                u32 v = local ? ld_sc0_u32(gf + tid) : ldg_sc1_u32(gf + tid);
                if (__all(v >= g)) break;
            }
        }
        __syncthreads();
    };

    // ---- x-half GEMM: bf16 cached loads (read-only data), K 0..511 ----
    auto xgemm = [&](int t, f32x4& c0, f32x4& c1) {
        const u16* xr = xbf + ((size_t)t * B_ + grp * 8 + (rl & 7)) * 512;
#pragma unroll
        for (int kc = 0; kc < 16; ++kc) {
            short8v a = *(const short8v*)(xr + kc * 32 + kg * 8);
            if (kc & 1) c1 = __builtin_amdgcn_mfma_f32_16x16x32_bf16(a, bw[kc], c1, 0, 0, 0);
            else        c0 = __builtin_amdgcn_mfma_f32_16x16x32_bf16(a, bw[kc], c0, 0, 0, 0);
        }
    };

    f32x4 xa0 = {0.f, 0.f, 0.f, 0.f}, xa1 = {0.f, 0.f, 0.f, 0.f};
    g_arrive(1);
    xgemm(0, xa0, xa1);
    g_wait(1);

    for (int t = 0; t < T_; ++t) {
        const u32 genA = 2 + 2 * t, genB = 3 + 2 * t;

        // ===== phase 1: h-half GEMM (K 512..1023) accumulated into xa =====
        {
            const u16* hrow = grp_h + (rl & 7) * 512;
#pragma unroll
            for (int half = 0; half < 2; ++half) {
                short8v a0, a1, a2, a3, a4, a5, a6, a7;
                const u16* hb = hrow + half * 256 + kg * 8;
                if (local) {
                    asm volatile("global_load_dwordx4 %0, %1, off sc0" : "=v"(a0) : "v"(hb) : "memory");
                    asm volatile("global_load_dwordx4 %0, %1, off sc0" : "=v"(a1) : "v"(hb + 32) : "memory");
                    asm volatile("global_load_dwordx4 %0, %1, off sc0" : "=v"(a2) : "v"(hb + 64) : "memory");
                    asm volatile("global_load_dwordx4 %0, %1, off sc0" : "=v"(a3) : "v"(hb + 96) : "memory");
                    asm volatile("global_load_dwordx4 %0, %1, off sc0" : "=v"(a4) : "v"(hb + 128) : "memory");
                    asm volatile("global_load_dwordx4 %0, %1, off sc0" : "=v"(a5) : "v"(hb + 160) : "memory");
                    asm volatile("global_load_dwordx4 %0, %1, off sc0" : "=v"(a6) : "v"(hb + 192) : "memory");
                    asm volatile("global_load_dwordx4 %0, %1, off sc0" : "=v"(a7) : "v"(hb + 224) : "memory");
                    asm volatile("s_waitcnt vmcnt(0)" ::: "memory");
                    __builtin_amdgcn_sched_barrier(0);
                } else {
                    union { u64 q[2]; short8v v; } u;
#define LDH(dst, off) u.q[0] = ldg_sc1_u64(hb + (off)); u.q[1] = ldg_sc1_u64(hb + (off) + 4); dst = u.v;
                    LDH(a0, 0) LDH(a1, 32) LDH(a2, 64) LDH(a3, 96)
                    LDH(a4, 128) LDH(a5, 160) LDH(a6, 192) LDH(a7, 224)
#undef LDH
                }
                const int kb = 16 + half * 8;
                xa0 = __builtin_amdgcn_mfma_f32_16x16x32_bf16(a0, bw[kb + 0], xa0, 0, 0, 0);
                xa1 = __builtin_amdgcn_mfma_f32_16x16x32_bf16(a1, bw[kb + 1], xa1, 0, 0, 0);
                xa0 = __builtin_amdgcn_mfma_f32_16x16x32_bf16(a2, bw[kb + 2], xa0, 0, 0, 0);
                xa1 = __builtin_amdgcn_mfma_f32_16x16x32_bf16(a3, bw[kb + 3], xa1, 0, 0, 0);
                xa0 = __builtin_amdgcn_mfma_f32_16x16x32_bf16(a4, bw[kb + 4], xa0, 0, 0, 0);
                xa1 = __builtin_amdgcn_mfma_f32_16x16x32_bf16(a5, bw[kb + 5], xa1, 0, 0, 0);
                xa0 = __builtin_amdgcn_mfma_f32_16x16x32_bf16(a6, bw[kb + 6], xa0, 0, 0, 0);
                xa1 = __builtin_amdgcn_mfma_f32_16x16x32_bf16(a7, bw[kb + 7], xa1, 0, 0, 0);
            }
        }
        f32x4 acc = xa0 + xa1;

        float v4[4], sj[4], qj[4];
#pragma unroll
        for (int j = 0; j < 4; ++j) {
            v4[j] = acc[j] + bcol;
            sj[j] = v4[j]; qj[j] = v4[j] * v4[j];
        }
        if (kg < 2) {
#pragma unroll
            for (int j = 0; j < 4; ++j) ldsC[w][kg * 4 + j][rl] = v4[j];
        }
#pragma unroll
        for (int m = 1; m < 16; m <<= 1) {
#pragma unroll
            for (int j = 0; j < 4; ++j) {
                sj[j] += __shfl_xor(sj[j], m);
                qj[j] += __shfl_xor(qj[j], m);
            }
        }
        if (rl == 0 && kg < 2) {
#pragma unroll
            for (int j = 0; j < 4; ++j) sp[w][kg * 4 + j] = f32x2{sj[j], qj[j]};
        }
        __syncthreads();
        if (tid < 8) {       // per-wg stats: one float2 per row
            float S = sp[0][tid].x + sp[1][tid].x + sp[2][tid].x + sp[3][tid].x;
            float Q = sp[0][tid].y + sp[1][tid].y + sp[2][tid].y + sp[3][tid].y;
            union { float f[2]; u64 q; } uu; uu.f[0] = S; uu.f[1] = Q;
            u64* dst = (u64*)(grp_s + (tid * 32 + slot) * 2);
            if (local) st_sc0_u64(dst, uu.q); else stg_sc1_u64(dst, uu.q);
        }
        asm volatile("s_waitcnt vmcnt(0)" ::: "memory");
        if (tid == 0) { if (local) st_sc0_u32(gf + slot, genA); else stg_sc1_u32(gf + slot, genA); }

        // prefetch x-half of t+1 while waiting
        if (t + 1 < T_) {
            xa0 = f32x4{0.f, 0.f, 0.f, 0.f}; xa1 = f32x4{0.f, 0.f, 0.f, 0.f};
            xgemm(t + 1, xa0, xa1);
        }
        g_wait(genA);

        // ===== phase 2: stats reduce + LN + gates + state =====
        {
            const float* p = grp_s + (((tid >> 5) * 32 + (tid & 31)) * 2);
            f32x2 pv;
            if (local) pv = ld_sc0_f32x2(p);
            else { union { u64 q; float f[2]; } uu; uu.q = ldg_sc1_u64(p); pv.x = uu.f[0]; pv.y = uu.f[1]; }
            float s = pv.x, q = pv.y;
#pragma unroll
            for (int m = 1; m < 32; m <<= 1) {
                s += __shfl_xor(s, m);
                q += __shfl_xor(q, m);
            }
            if ((tid & 31) == 0) sstat[tid >> 5] = f32x2{s, q};
        }
        __syncthreads();

        if (tid < 128) {
            float S = sstat[pb].x, Q = sstat[pb].y;
            float mu = S * (1.0f / 2048.0f);
            float var = Q * (1.0f / 2048.0f) - mu * mu;
            float rstd = rsqrtf(var + EPSF);
            float g0 = (ldsC[0][pb][pi] - mu) * rstd * lw0 + lb0;
            float g1 = (ldsC[1][pb][pi] - mu) * rstd * lw1 + lb1;
            float g2 = (ldsC[2][pb][pi] - mu) * rstd * lw2 + lb2;
            float g3 = (ldsC[3][pb][pi] - mu) * rstd * lw3 + lb3;
            float ig = 1.f / (1.f + __expf(-g0));
            float fg = 1.f / (1.f + __expf(-g1));
            float og = 1.f / (1.f + __expf(-g2));
            float e2 = __expf(-2.f * fabsf(g3));
            float th = copysignf((1.f - e2) / (1.f + e2), g3);
            creg = fg * creg + ig * th;
            float h = og * creg;
            __builtin_nontemporal_store(h, out + (size_t)(grp * 8 + pb) * (T_ * O_) + (size_t)t * O_ + po);
            if (t + 1 < T_) {
                float hn = __shfl_xor(h, 1);
                if (!(pi & 1)) {
                    u32 hp = (u32)f2bf(h) | ((u32)f2bf(hn) << 16);
                    u32* dst = (u32*)(grp_h + pb * 512 + po);
                    if (local) st_sc0_u32(dst, hp); else stg_sc1_u32(dst, hp);
                }
            }
        }

        if (t == T_ - 1) break;
        g_arrive(genB);
        g_wait(genB);
    }
}

extern "C" void kernel_launch(void* const* d_in, const int* in_sizes, int n_in,
                              void* d_out, int out_size, void* d_ws, size_t ws_size,
                              hipStream_t stream) {
    const float* x    = (const float*)d_in[0];
    const float* W    = (const float*)d_in[1];
    const float* bias = (const float*)d_in[2];
    const float* lnw  = (const float*)d_in[3];
    const float* lnb  = (const float*)d_in[4];
    const float* hx   = (const float*)d_in[5];
    const float* cx   = (const float*)d_in[6];
    float* out = (float*)d_out;

    char* ws = (char*)d_ws;
    u16*   wt    = (u16*)ws;                      // 4 MiB
    u16*   xbf   = (u16*)(ws + 4194304);          // 32 MiB [t][b][k]
    u16*   hbuf  = (u16*)(ws + 37748736);         // 64 KiB (8 grp x 8 KiB)
    float* stats = (float*)(ws + 37814272);       // 16 KiB (8 grp x 2 KiB)
    u32*   ctrl  = (u32*)(ws + 37830656);         // 8 KiB: gflags|xcct|testw|grpfl

    k_init_wt<<<512, 256, 0, stream>>>(W, wt);
    k_init_x<<<8192, 256, 0, stream>>>(x, xbf);
    k_zero<<<8, 256, 0, stream>>>(ctrl);
    k_persist<<<NWG, NTHR, 0, stream>>>(xbf, wt, bias, lnw, lnb, hx, cx,
                                        hbuf, stats, ctrl, out);
}